// Round 1
// baseline (173.004 us; speedup 1.0000x reference)
//
#include <hip/hip_runtime.h>

#define NCAP 10     // capsule classes c
#define NB   256    // batch b
#define NN   1152   // route nodes n
#define KI   8      // input dim i
#define NO   16     // output dim o
#define NLP  72     // n per thread = NN/16
#define NITER 3

__global__ __launch_bounds__(256) void capsule_kernel(
    const float* __restrict__ x,    // [256,1152,8]
    const float* __restrict__ w,    // [10,1152,8,16]
    float* __restrict__ out)        // [10,256,16]
{
    __shared__ float s_x[NN * KI];      // 36 KB: x[b] staged
    __shared__ float s_logit[NN];       // 4.5 KB
    __shared__ float s_red[4];          // per-wave scalar partials
    __shared__ float s_red2[4][NO];     // per-wave per-o partials

    const int t    = threadIdx.x;
    const int o    = t & 15;
    const int ng   = t >> 4;
    const int wave = t >> 6;
    const int lane = t & 63;

    // XCD-aware swizzle: 2560 blocks % 8 == 0 -> bijective; same-c blocks
    // cluster on one XCD so W[c] (576 KB) stays L2-resident.
    const int bid = blockIdx.x;
    const int swz = (bid & 7) * (NCAP * NB / 8) + (bid >> 3);
    const int c = swz / NB;
    const int b = swz % NB;

    // stage x[b] into LDS: 9216 floats = 2304 float4, 9 per thread
    {
        const float4* xs = reinterpret_cast<const float4*>(x + (size_t)b * NN * KI);
        float4* xd = reinterpret_cast<float4*>(s_x);
        #pragma unroll
        for (int k = 0; k < 9; ++k) xd[t + 256 * k] = xs[t + 256 * k];
    }
    // init logits to 0
    #pragma unroll
    for (int k = 0; k < 4; ++k) s_logit[t + 256 * k] = 0.f;
    if (t < 128) s_logit[1024 + t] = 0.f;
    __syncthreads();

    // priors[nl] = x[b, n, :] . W[c, n, :, o],  n = nl*16 + ng
    float prior[NLP];
    #pragma unroll
    for (int nl = 0; nl < NLP; ++nl) {
        const int n = nl * 16 + ng;
        const float* wp = w + (((size_t)c * NN + n) * KI) * NO + o;
        float acc = 0.f;
        #pragma unroll
        for (int i = 0; i < KI; ++i)
            acc = fmaf(s_x[n * KI + i], wp[i * NO], acc);
        prior[nl] = acc;
    }

    float v = 0.f;  // this thread's output component (for its o)
    for (int iter = 0; iter < NITER; ++iter) {
        // ---- softmax stats over s_logit[0..1151] ----
        float lmax = -1e30f;
        #pragma unroll
        for (int nl = 0; nl < NLP; ++nl)
            lmax = fmaxf(lmax, s_logit[nl * 16 + ng]);
        #pragma unroll
        for (int m = 1; m < 64; m <<= 1)
            lmax = fmaxf(lmax, __shfl_xor(lmax, m));
        if (lane == 0) s_red[wave] = lmax;
        __syncthreads();
        lmax = fmaxf(fmaxf(s_red[0], s_red[1]), fmaxf(s_red[2], s_red[3]));

        float lsum = 0.f;
        #pragma unroll
        for (int nl = 0; nl < NLP; ++nl)
            lsum += __expf(s_logit[nl * 16 + ng] - lmax);
        #pragma unroll
        for (int m = 1; m < 64; m <<= 1)
            lsum += __shfl_xor(lsum, m);
        __syncthreads();                 // protect s_red before rewrite
        if (lane == 0) s_red[wave] = lsum;
        __syncthreads();
        // each n counted 16x (once per o-lane) -> true sum = total/16
        const float inv_sum = 16.0f / (s_red[0] + s_red[1] + s_red[2] + s_red[3]);

        // ---- weighted sum over n for this thread's o ----
        float sp = 0.f;
        #pragma unroll
        for (int nl = 0; nl < NLP; ++nl)
            sp = fmaf(__expf(s_logit[nl * 16 + ng] - lmax), prior[nl], sp);
        // reduce across ng within wave (lanes o, o+16, o+32, o+48)
        sp += __shfl_xor(sp, 16);
        sp += __shfl_xor(sp, 32);
        if (lane < 16) s_red2[wave][lane] = sp;
        __syncthreads();
        const float s_o =
            (s_red2[0][o] + s_red2[1][o] + s_red2[2][o] + s_red2[3][o]) * inv_sum;

        // ---- squash ----
        float sq = s_o * s_o;
        sq += __shfl_xor(sq, 1);
        sq += __shfl_xor(sq, 2);
        sq += __shfl_xor(sq, 4);
        sq += __shfl_xor(sq, 8);
        const float scale = sq / ((1.0f + sq) * sqrtf(sq));
        v = s_o * scale;

        if (iter < NITER - 1) {
            // ---- logit update: logit[n] += priors[n,:] . v ----
            #pragma unroll
            for (int nl = 0; nl < NLP; ++nl) {
                float d = prior[nl] * v;
                d += __shfl_xor(d, 1);
                d += __shfl_xor(d, 2);
                d += __shfl_xor(d, 4);
                d += __shfl_xor(d, 8);
                if (o == 0) s_logit[nl * 16 + ng] += d;
            }
            __syncthreads();
        }
    }

    // output: [c, b, 1, 1, o]
    if (t < 16) out[((size_t)c * NB + b) * NO + t] = v;
}

extern "C" void kernel_launch(void* const* d_in, const int* in_sizes, int n_in,
                              void* d_out, int out_size, void* d_ws, size_t ws_size,
                              hipStream_t stream) {
    const float* x = (const float*)d_in[0];
    const float* w = (const float*)d_in[1];
    float* out = (float*)d_out;
    capsule_kernel<<<dim3(NCAP * NB), dim3(256), 0, stream>>>(x, w, out);
}